// Round 7
// baseline (102.594 us; speedup 1.0000x reference)
//
#include <hip/hip_runtime.h>

// Match numpy f32 semantics exactly: no FMA contraction anywhere in this file.
#pragma clang fp contract(off)

#define NBOX   1024
#define NCLS   32
#define NBATCH 8
#define MAXOUT 300
#define SMAX   11   // fast path handles V <= 704 (Binom(1024,.5): mean 512, sd 16)
#define MAGIC  0x600DF00Du   // != 0xAAAAAAAA ws-poison => no flag init needed

// Exact all-f32 replacement for the reference's  RN(inter/denom) > 0.5f :
//   RN(I/D) > 0.5  <=>  I/D > 0.5*(1+2^-24)      (RN monotone; midpoint
//   quotients unreachable for f32 operands)      <=>  2I - D > D*2^-24.
//   lhs = RN(2I-D) exact by Sterbenz for I/D in [1/4,1], sign-correct below;
//   rhs = RN(D*2^-24) exact exponent shift. Verified absmax 0.0 in round 6.
#define IOU_SUP(ab, aa, bj, arj, act, acc) do {               \
    float yy1 = fmaxf((ab).x, (bj).x);                        \
    float xx1 = fmaxf((ab).y, (bj).y);                        \
    float yy2 = fminf((ab).z, (bj).z);                        \
    float xx2 = fminf((ab).w, (bj).w);                        \
    float ih = fmaxf(yy2 - yy1, 0.0f);                        \
    float iw = fmaxf(xx2 - xx1, 0.0f);                        \
    float inter = ih * iw;                                    \
    float denom = ((aa) + (arj)) - inter;                     \
    float lhs = (inter + inter) - denom;                      \
    float rhs = denom * 5.9604644775390625e-08f;              \
    if ((act) && (lhs > rhs)) (acc) |= bit;                   \
  } while (0)

// 64-bit shfl_xor built from two 32-bit shfls (deterministic, wave64).
__device__ __forceinline__ unsigned long long shflx64(unsigned long long v, int m) {
  unsigned lo = (unsigned)__shfl_xor((int)(unsigned)v, m, 64);
  unsigned hi = (unsigned)__shfl_xor((int)(unsigned)(v >> 32), m, 64);
  return ((unsigned long long)hi << 32) | lo;
}

// Bitonic compare-exchange in registers; final order descending. Keys unique.
__device__ __forceinline__ unsigned long long cexch(
    unsigned long long mine, int jj, int kk, int t) {
  unsigned long long other = shflx64(mine, jj);
  bool iLow = ((t & jj) == 0);
  bool desc = ((t & kk) == 0);
  bool wantMax = (iLow == desc);
  bool otherBigger = (other > mine);
  return (wantMax == otherBigger) ? other : mine;
}

// Fused: 256 blocks x 1024 threads. Every block: per-(batch,class) NMS into
// recs + RELEASE flag. Blocks with c==0 additionally wait for their batch's
// 32 flags and run the top-300 selection + output. Swizzle b = bc&7 puts a
// whole batch on one XCD (XCD = bc%8): score lines fetched once per XCD,
// recs traffic XCD-local, consumers spread one per XCD.
__global__ __launch_bounds__(1024) void nms_fused(
    const float* __restrict__ boxes, const float* __restrict__ scores,
    unsigned long long* __restrict__ recs, unsigned int* __restrict__ flags,
    float* __restrict__ out) {
#pragma clang fp contract(off)
  const int bc = blockIdx.x;
  const int b = bc & (NBATCH - 1);   // XCD-aligned batch
  const int c = bc >> 3;
  const int t = threadIdx.x;
  const int lane = t & 63, wav = t >> 6;

  // Phase-overlaid LDS (phase 1: 63488 B; phase 2: 34832 B).
  __shared__ __align__(16) unsigned char shraw[63488];
  unsigned long long* key = (unsigned long long*)shraw;                 // 8192
  float4* sbox            = (float4*)(shraw + 8192);                    // 16384
  float* sarea            = (float*)(shraw + 24576);                    // 4096
  unsigned long long* mask = (unsigned long long*)(shraw + 28672);      // 34816
  __shared__ unsigned long long kb[16];
  __shared__ int shV;

  // ---------- Phase 1: per-class NMS (identical math to round 6) ----------
  const float* sp = scores + (size_t)b * NBOX * NCLS + c;
  float s = sp[(size_t)t * NCLS];
  bool valid = (s > 0.5f);
  unsigned long long mine = valid
      ? ((((unsigned long long)__float_as_uint(s)) << 32) | (unsigned)(NBOX - 1 - t))
      : (unsigned long long)(unsigned)(NBOX - 1 - t);
  if (t == 0) shV = 0;
  if (t < 16) kb[t] = 0ull;
  __syncthreads();
  unsigned long long vb = __ballot(valid);
  if (lane == 0) atomicAdd(&shV, (int)__popcll(vb));

  // Bitonic sort, descending. jj<=32 stages in registers; 10 LDS stages.
  for (int kk = 2; kk <= 64; kk <<= 1)
    for (int jj = kk >> 1; jj > 0; jj >>= 1)
      mine = cexch(mine, jj, kk, t);
  key[t] = mine;
  __syncthreads();
  for (int kk = 128; kk <= 1024; kk <<= 1) {
    for (int jj = kk >> 1; jj >= 64; jj >>= 1) {
      if (t < 512) {
        int i = ((t & ~(jj - 1)) << 1) | (t & (jj - 1));
        int ixj = i | jj;
        unsigned long long a = key[i], bb = key[ixj];
        if (((i & kk) == 0) ? (a < bb) : (a > bb)) { key[i] = bb; key[ixj] = a; }
      }
      __syncthreads();
    }
    mine = key[t];
    for (int jj = 32; jj > 0; jj >>= 1) mine = cexch(mine, jj, kk, t);
    key[t] = mine;
    __syncthreads();
  }

  // Gather boxes in sorted order; precompute areas (same expression as ref).
  int n0 = NBOX - 1 - (int)(mine & (NBOX - 1));
  const float4* gb = (const float4*)boxes + (size_t)b * NBOX;
  float4 bx4 = gb[n0];
  sbox[t] = bx4;
  sarea[t] = (bx4.z - bx4.x) * (bx4.w - bx4.y);
  __syncthreads();
  const int V = shV;
  const int S = (V + 63) >> 6;
  const bool aj = (t < V);

  unsigned long long mext[15];
  unsigned long long mself = 0ull;
#pragma unroll
  for (int w = 0; w < 15; ++w) mext[w] = 0ull;

  if (S <= SMAX) {
    // Chunk = (I-strip, up to 3 consecutive J-strips): broadcast reads of
    // strip I amortized over 3 IoUs (LDS-pipe load ~3x lower).
    int NC = 0;
    for (int I2 = 0; I2 < S; ++I2) NC += (S - I2 + 2) / 3;
    for (int k = wav; k < NC; k += 16) {
      int I = 0, rem = k;
      for (;;) { int cI = (S - I + 2) / 3; if (rem < cI) break; rem -= cI; ++I; }
      const int J0 = I + 3 * rem;
      const bool h1 = (J0 + 1 < S), h2 = (J0 + 2 < S);
      const int j0 = (J0 << 6) + lane;
      const int j1 = h1 ? j0 + 64 : j0;
      const int j2 = h2 ? j0 + 128 : j0;
      const float4 b0 = sbox[j0]; const float ar0 = sarea[j0];
      const float4 b1 = sbox[j1]; const float ar1 = sarea[j1];
      const float4 b2 = sbox[j2]; const float ar2 = sarea[j2];
      const bool act0 = (j0 < V);
      const bool act1 = h1 && (j0 + 64 < V);
      const bool act2 = h2 && (j0 + 128 < V);
      const float4* bi = &sbox[I << 6];
      const float* ai = &sarea[I << 6];
      unsigned long long a0 = 0, a1 = 0, a2 = 0;
      unsigned long long bit = 1ull;
#pragma unroll 8
      for (int q = 0; q < 64; ++q) {
        float4 ab = bi[q];      // ds_read_b128, uniform addr -> broadcast
        float aa = ai[q];       // ds_read_b32,  uniform addr -> broadcast
        IOU_SUP(ab, aa, b0, ar0, act0, a0);
        IOU_SUP(ab, aa, b1, ar1, act1, a1);
        IOU_SUP(ab, aa, b2, ar2, act2, a2);
        bit <<= 1;
      }
      if (rem == 0) a0 &= (1ull << lane) - 1ull;  // diagonal: enforce i<j
      const int vrem = V - (I << 6);              // tail strip: mask i>=V
      if (vrem < 64) {
        unsigned long long tm = (1ull << vrem) - 1ull;
        a0 &= tm; a1 &= tm; a2 &= tm;
      }
      mask[(((J0 * (J0 + 1) / 2) << 6) + lane * (J0 + 1)) + I] = a0;
      if (h1) mask[((((J0 + 1) * (J0 + 2) / 2) << 6) + lane * (J0 + 2)) + I] = a1;
      if (h2) mask[((((J0 + 2) * (J0 + 3) / 2) << 6) + lane * (J0 + 3)) + I] = a2;
    }
    __syncthreads();
    if (t < (S << 6)) {                 // wave-uniform branch (J per wave)
      const int J = wav;
      const int rbs = ((J * (J + 1) / 2) << 6) + lane * (J + 1);
#pragma unroll
      for (int I = 0; I < 15; ++I)      // static index: mext stays in VGPRs
        if (I < J) mext[I] = mask[rbs + I];
      mself = mask[rbs + J];            // diagonal word (bits < lane only)
    }
  } else {
    // Fallback (V > 704; statistically unreachable): per-thread strips.
    const int J = wav;
    const float4 bj = sbox[t];
    const float arj = sarea[t];
#pragma unroll
    for (int I = 0; I < 16; ++I) {
      if (I <= J && (I << 6) < V) {
        unsigned long long acc = 0, bit = 1ull;
        for (int q = 0; q < 64; ++q) {
          int i = (I << 6) + q;
          float4 ab = sbox[i];
          float aa = sarea[i];
          bool act = aj && (i < t) && (i < V);
          IOU_SUP(ab, aa, bj, arj, act, acc);
          bit <<= 1;
        }
        if (I == J) mself = acc;
        else mext[I] = acc;
      }
    }
  }
  __syncthreads();

  // Word-sequential Gauss-Seidel resolve == exact greedy NMS.
  for (int w = 0; w < S; ++w) {
    if (wav == w) {
      bool supExt = false;
#pragma unroll
      for (int i = 0; i < 15; ++i)
        if (i < w) supExt = supExt || ((mext[i] & kb[i]) != 0ull);
      bool alive = aj && !supExt;
      unsigned long long cur = __ballot(alive);
      for (;;) {
        unsigned long long nb = __ballot(alive && ((mself & cur) == 0ull));
        if (nb == cur) break;
        cur = nb;
      }
      if (lane == 0) kb[w] = cur;
    }
    __syncthreads();
  }

  // Emit kept records (class rank < 300), zero-fill tail.
  unsigned long long kbr[16];
#pragma unroll
  for (int w = 0; w < 16; ++w) kbr[w] = kb[w];
  int tot = 0;
#pragma unroll
  for (int w = 0; w < 16; ++w) tot += (int)__popcll(kbr[w]);
  const size_t rbase = ((size_t)b * NCLS + c) * MAXOUT;
  unsigned long long kw = kbr[0];
#pragma unroll
  for (int w = 1; w < 16; ++w) if (w == wav) kw = kbr[w];
  if (aj && ((kw >> lane) & 1ull)) {
    int rank = 0;
#pragma unroll
    for (int w = 0; w < 16; ++w)
      if (w < wav) rank += (int)__popcll(kbr[w]);
    rank += (int)__popcll(kw & ((1ull << lane) - 1ull));
    if (rank < MAXOUT) {
      unsigned sbits = (unsigned)(mine >> 32);
      int n = NBOX - 1 - (int)(mine & (NBOX - 1));
      int flat = c * NBOX + t;
      recs[rbase + rank] = (((unsigned long long)sbits) << 32)
          | ((unsigned)(NCLS * NBOX - 1 - flat) << 10) | (unsigned)n;
    }
  }
  if (t < MAXOUT && t >= tot) recs[rbase + t] = 0ull;

  // Signal: syncthreads drains all waves' stores (vmcnt(0)), then one
  // agent-scope RELEASE store makes them device-visible.
  __syncthreads();
  if (t == 0)
    __hip_atomic_store(&flags[bc], MAGIC, __ATOMIC_RELEASE,
                       __HIP_MEMORY_SCOPE_AGENT);
  if (c != 0) return;

  // ---------- Phase 2 (consumer, one block per batch): top-300 ----------
  if (t < NCLS)
    while (__hip_atomic_load(&flags[(t << 3) + b], __ATOMIC_ACQUIRE,
                             __HIP_MEMORY_SCOPE_AGENT) != MAGIC)
      __builtin_amdgcn_s_sleep(8);
  __syncthreads();

  // LDS overlay for phase 2.
  int* histw              = (int*)shraw;                       // 16384
  int* hist               = (int*)(shraw + 16384);             // 1024
  int* suf                = (int*)(shraw + 17408);             // 1028
  unsigned long long* maxKey = (unsigned long long*)(shraw + 18448);  // 8192
  unsigned long long* blist  = (unsigned long long*)(shraw + 26640);  // 8192
  __shared__ int bcnt;
  __shared__ unsigned long long shT;
  __shared__ int shBstar;
  __shared__ int wcnt[16], woff[16];
  __shared__ int shPresTot;

  const int CAND = NCLS * MAXOUT;
  unsigned long long* rb = recs + (size_t)b * NCLS * MAXOUT;
  unsigned long long cand[10];
#pragma unroll
  for (int q = 0; q < 10; ++q) {
    int j = t + (q << 10);
    // Agent-scope relaxed loads: bypass any stale XCD-local cache.
    cand[q] = (j < CAND)
        ? __hip_atomic_load(&rb[j], __ATOMIC_RELAXED, __HIP_MEMORY_SCOPE_AGENT)
        : 0ull;
  }
  maxKey[t] = 0;
#pragma unroll
  for (int q = 0; q < 4; ++q) histw[t + (q << 10)] = 0;
  if (t == 0) { bcnt = 0; shT = 0; shBstar = -1; }
  __syncthreads();

  // Histogram on score-bit buckets (wave-private copies); score in (0.5,1)
  // => bits in (0x3F000000,0x3F800000) => bucket = (bits-0x3F000000)>>15.
#pragma unroll
  for (int q = 0; q < 10; ++q) {
    unsigned long long v = cand[q];
    if (v != 0ull) {
      int bk = (int)(((unsigned)(v >> 32) - 0x3F000000u) >> 15);
      atomicAdd(&histw[(wav << 8) + bk], 1);
    }
  }
  __syncthreads();
  if (t < 256) {
    int ssum = 0;
#pragma unroll
    for (int w = 0; w < 16; ++w) ssum += histw[(w << 8) + t];
    hist[t] = ssum;
  }
  __syncthreads();

  // Wave 0: suffix sums over the 256 buckets.
  if (wav == 0) {
    int h[4];
#pragma unroll
    for (int g = 0; g < 4; ++g) h[g] = hist[g * 64 + lane];
#pragma unroll
    for (int g = 0; g < 4; ++g) {
      int v = h[g];
#pragma unroll
      for (int off = 1; off < 64; off <<= 1) {
        int u = __shfl_down(v, off);
        if (lane + off < 64) v += u;
      }
      h[g] = v;                       // suffix within group
    }
    int sum1 = __shfl(h[1], 0);
    int sum2 = __shfl(h[2], 0);
    int sum3 = __shfl(h[3], 0);
    suf[0 * 64 + lane] = h[0] + sum1 + sum2 + sum3;
    suf[1 * 64 + lane] = h[1] + sum2 + sum3;
    suf[2 * 64 + lane] = h[2] + sum3;
    suf[3 * 64 + lane] = h[3];
    if (lane == 0) suf[256] = 0;
  }
  __syncthreads();

  // Boundary bucket B*: suf[B*] >= 300 > suf[B*+1]. (-1 if total < 300.)
  if (t < 256) {
    if (suf[t] >= MAXOUT && suf[t + 1] < MAXOUT) shBstar = t;
  }
  __syncthreads();
  const int Bstar = shBstar;

  if (Bstar >= 0) {   // block-uniform branch
#pragma unroll
    for (int q = 0; q < 10; ++q) {
      unsigned long long v = cand[q];
      if (v != 0ull) {
        int bk = (int)(((unsigned)(v >> 32) - 0x3F000000u) >> 15);
        if (bk == Bstar) { int idx = atomicAdd(&bcnt, 1); blist[idx] = v; }
      }
    }
    __syncthreads();
    int M = bcnt;
    int need = MAXOUT - suf[Bstar + 1];
    if (t < M) {
      unsigned long long mk = blist[t];
      int r = 0;
      for (int i = 0; i < M; ++i) r += (blist[i] > mk) ? 1 : 0;
      if (r == need - 1) shT = mk;     // the 300th-largest key overall
    }
    __syncthreads();
  }
  const unsigned long long T = shT;    // 0 => select all nonzero

  // Dedup by original box id: max key == earliest top-300 occurrence.
#pragma unroll
  for (int q = 0; q < 10; ++q) {
    unsigned long long v = cand[q];
    if (v != 0ull && v >= T) {
      int n = (int)(v & (NBOX - 1));
      atomicMax(&maxKey[n], v);
    }
  }
  __syncthreads();

  // Present flags -> output slot via ballot scan (box ids ascending).
  bool pres = (maxKey[t] != 0ull);
  unsigned long long wm = __ballot(pres);
  if (lane == 0) wcnt[wav] = (int)__popcll(wm);
  __syncthreads();
  if (t < 16) {
    int v = wcnt[t];
    int inc = v;
#pragma unroll
    for (int off = 1; off < 16; off <<= 1) {
      int u = __shfl_up(inc, off);
      if (lane >= off) inc += u;
    }
    woff[t] = inc - v;
    if (t == 15) shPresTot = inc;
  }
  __syncthreads();
  const int total = shPresTot;

  float* ob = out + (size_t)b * MAXOUT * 4;
  float* os = out + (size_t)NBATCH * MAXOUT * 4 + (size_t)b * MAXOUT;
  float* oc = out + (size_t)NBATCH * MAXOUT * 5 + (size_t)b * MAXOUT;

  if (pres) {
    int slot = woff[wav] + (int)__popcll(wm & ((1ull << lane) - 1ull));
    unsigned long long v = maxKey[t];
    float score = __uint_as_float((unsigned)(v >> 32));
    int flat = NCLS * NBOX - 1 - (int)((v >> 10) & (unsigned)(NCLS * NBOX - 1));
    int cls = flat >> 10;
    float4 bx = ((const float4*)boxes)[(size_t)b * NBOX + t];
    ob[slot * 4 + 0] = bx.x;
    ob[slot * 4 + 1] = bx.y;
    ob[slot * 4 + 2] = bx.z;
    ob[slot * 4 + 3] = bx.w;
    os[slot] = score;
    oc[slot] = (float)cls;
  }
  if (t >= total && t < MAXOUT) {
    ob[t * 4 + 0] = 0.0f; ob[t * 4 + 1] = 0.0f;
    ob[t * 4 + 2] = 0.0f; ob[t * 4 + 3] = 0.0f;
    os[t] = 0.0f;
    oc[t] = 0.0f;
  }
}

extern "C" void kernel_launch(void* const* d_in, const int* in_sizes, int n_in,
                              void* d_out, int out_size, void* d_ws, size_t ws_size,
                              hipStream_t stream) {
  const float* boxes  = (const float*)d_in[0];   // [8,1024,4] f32
  const float* scores = (const float*)d_in[1];   // [8,1024,32] f32
  float* out = (float*)d_out;                    // boxes ‖ scores ‖ classes (f32)

  unsigned long long* recs = (unsigned long long*)d_ws;  // 256*300 u64
  unsigned int* flags = (unsigned int*)((char*)d_ws +
      (size_t)NBATCH * NCLS * MAXOUT * sizeof(unsigned long long));  // 256 u32
  // flags start as 0xAAAAAAAA (ws poison) == "not ready"; producers store
  // MAGIC with agent-scope release. No init pass needed.

  nms_fused<<<NBATCH * NCLS, 1024, 0, stream>>>(boxes, scores, recs, flags, out);
}